// Round 3
// baseline (328.653 us; speedup 1.0000x reference)
//
#include <hip/hip_runtime.h>
#include <hip/hip_bf16.h>

// Problem: B=64, S=1024, H=1024, A=512, E=512
// scores = tanh(encoded@W_enc + b_enc + states@W_dec + b_dec) . w_out (+b_out: softmax-invariant)
// weights = softmax(scores); attention = weights . encoded
// GRU: x=[inputs,attention]; gi=x@W_ih+b_ih; gh=states@W_hh+b_hh; gates -> h_new

typedef __attribute__((ext_vector_type(8))) __bf16 bf16x8;
typedef __attribute__((ext_vector_type(4))) __bf16 bf16x4;
typedef __attribute__((ext_vector_type(4))) float f32x4;

__device__ __forceinline__ float fast_tanh(float x) {
  float xa = fminf(fmaxf(x, -15.f), 15.f);
  float e = __expf(2.f * xa);
  return (e - 1.f) / (e + 1.f);
}

// ---------------- Kernel T: transpose+convert W_enc [1024][512] f32 -> Wt [512][1024] bf16
__global__ __launch_bounds__(256) void wenc_t_kernel(const float* __restrict__ W,
                                                     __bf16* __restrict__ Wt) {
  __shared__ float tile[32][33];
  int k0 = blockIdx.x * 32, a0 = blockIdx.y * 32;
  int tid = threadIdx.x;
  int r = tid >> 3, c4 = (tid & 7) * 4;
  f32x4 v = *(const f32x4*)(W + (long)(k0 + r) * 512 + a0 + c4);
  tile[r][c4 + 0] = v.x; tile[r][c4 + 1] = v.y;
  tile[r][c4 + 2] = v.z; tile[r][c4 + 3] = v.w;
  __syncthreads();
  int a = tid >> 3, k4 = (tid & 7) * 4;
  bf16x4 o = { (__bf16)tile[k4 + 0][a], (__bf16)tile[k4 + 1][a],
               (__bf16)tile[k4 + 2][a], (__bf16)tile[k4 + 3][a] };
  *(bf16x4*)(Wt + (long)(a0 + a) * 1024 + k0 + k4) = o;
}

// ---------------- Kernel A: addv[b][a] = b_enc[a]+b_dec[a]+sum_h states[b,h]*W_dec[h,a]
__global__ __launch_bounds__(256) void dec_proj_kernel(
    const float* __restrict__ states, const float* __restrict__ W_dec,
    const float* __restrict__ b_enc, const float* __restrict__ b_dec,
    float* __restrict__ addv) {
  int b = blockIdx.x, tid = threadIdx.x;
  int a = blockIdx.y * 256 + tid;
  __shared__ float sl[1024];
  for (int i = tid; i < 1024; i += 256) sl[i] = states[b * 1024 + i];
  __syncthreads();
  float c0 = 0.f, c1 = 0.f, c2 = 0.f, c3 = 0.f;
#pragma unroll 4
  for (int i = 0; i < 256; ++i) {
    c0 += sl[i]         * W_dec[(i)        * 512 + a];
    c1 += sl[i + 256]   * W_dec[(i + 256)  * 512 + a];
    c2 += sl[i + 512]   * W_dec[(i + 512)  * 512 + a];
    c3 += sl[i + 768]   * W_dec[(i + 768)  * 512 + a];
  }
  addv[b * 512 + a] = c0 + c1 + c2 + c3 + b_enc[a] + b_dec[a];
}

// ---------------- Kernel B: 128x128 tile, BK=32, 8 waves (2x4), depth-2 reg prefetch,
// raw s_barrier + counted vmcnt (no vmcnt drain in loop), XOR-swizzled LDS, setprio MFMA.
// LDS: As0@0, As1@8192, Bs0@16384, Bs1@24576 (each [128 rows][32 bf16] = 8KB), red@32768.
__global__ __launch_bounds__(512, 4) void enc_score_kernel(
    const float* __restrict__ encoded,  // [65536][1024] f32
    const __bf16* __restrict__ Wt,      // [512][1024] bf16 (W_enc^T)
    const float* __restrict__ addv,     // [64][512]
    const float* __restrict__ w_out,    // [512]
    float* __restrict__ psc)            // [4][65536]
{
  __shared__ __attribute__((aligned(16))) char smem[34816];
  float* red = (float*)(smem + 32768);  // [128][4]

  const int d = blockIdx.x;
  const int xcd = d & 7;
  const int slot = d >> 3;
  const int bn = slot & 3;
  const int bm = ((slot >> 2) << 3) | xcd;  // bn-siblings share bm AND xcd

  const int tid = threadIdx.x;
  const int lane = tid & 63;
  const int wid = tid >> 6;       // 0..7
  const int wrow = wid >> 2;      // 0..1 (64 rows)
  const int wcol = wid & 3;       // 0..3 (32 cols)
  const int lr = lane & 15;
  const int lkb = lane >> 4;      // 0..3

  const long row0 = (long)bm * 128;
  const int col0 = bn * 128;

  // staging: thread t handles 8 contiguous k of row (t>>2), k-group (t&3)
  const int srow = tid >> 2;      // 0..127
  const int sk = tid & 3;         // 0..3 (x8 elems)
  const float* aBase = encoded + (row0 + srow) * 1024 + sk * 8;
  const __bf16* bBase = Wt + (long)(col0 + srow) * 1024 + sk * 8;
  // swizzled LDS byte offset for staging write (row stride 64B, 16B slots)
  const int wrOff = srow * 64 + ((sk ^ ((srow >> 1) & 3)) << 4);

  // fragment read offsets (phase independent of m/n since rows step by 16)
  const int aph = ((wrow * 64 + lr) >> 1) & 3;
  const int aRd = (wrow * 64 + lr) * 64 + ((lkb ^ aph) << 4);  // + m*1024
  const int bph = ((wcol * 32 + lr) >> 1) & 3;
  const int bRd = (wcol * 32 + lr) * 64 + ((lkb ^ bph) << 4);  // + n*1024

  f32x4 acc[4][2];
#pragma unroll
  for (int m = 0; m < 4; ++m)
#pragma unroll
    for (int n = 0; n < 2; ++n) acc[m][n] = (f32x4){0.f, 0.f, 0.f, 0.f};

  f32x4 a0A, a1A; bf16x8 bA;  // set0: tiles 0,2,4,...
  f32x4 a0B, a1B; bf16x8 bB;  // set1: tiles 1,3,5,...

#define ISSUE(A0, A1, BV, KT) { \
    const float* _pa = aBase + (KT) * 32; \
    A0 = *(const f32x4*)_pa; \
    A1 = *(const f32x4*)(_pa + 4); \
    BV = *(const bf16x8*)(bBase + (KT) * 32); }

#define STORE(A0, A1, BV, BUFOFF) { \
    bf16x8 _wv; \
    _wv[0] = (__bf16)A0.x; _wv[1] = (__bf16)A0.y; _wv[2] = (__bf16)A0.z; _wv[3] = (__bf16)A0.w; \
    _wv[4] = (__bf16)A1.x; _wv[5] = (__bf16)A1.y; _wv[6] = (__bf16)A1.z; _wv[7] = (__bf16)A1.w; \
    *(bf16x8*)(smem + (BUFOFF) + wrOff) = _wv; \
    *(bf16x8*)(smem + 16384 + (BUFOFF) + wrOff) = BV; }

#define COMPUTE(BUFOFF) { \
    bf16x8 _af[4], _bf[2]; \
    _Pragma("unroll") for (int _m = 0; _m < 4; ++_m) \
      _af[_m] = *(const bf16x8*)(smem + (BUFOFF) + aRd + _m * 1024); \
    _Pragma("unroll") for (int _n = 0; _n < 2; ++_n) \
      _bf[_n] = *(const bf16x8*)(smem + 16384 + (BUFOFF) + bRd + _n * 1024); \
    asm volatile("s_waitcnt lgkmcnt(0)" ::: "memory"); \
    __builtin_amdgcn_sched_barrier(0); \
    __builtin_amdgcn_s_setprio(1); \
    _Pragma("unroll") for (int _m = 0; _m < 4; ++_m) \
      _Pragma("unroll") for (int _n = 0; _n < 2; ++_n) \
        acc[_m][_n] = __builtin_amdgcn_mfma_f32_16x16x32_bf16(_af[_m], _bf[_n], acc[_m][_n], 0, 0, 0); \
    __builtin_amdgcn_s_setprio(0); }

#define BAR() { \
    asm volatile("s_waitcnt lgkmcnt(0)" ::: "memory"); \
    __builtin_amdgcn_sched_barrier(0); \
    __builtin_amdgcn_s_barrier(); \
    __builtin_amdgcn_sched_barrier(0); }

  // prologue: tiles 0,1 in flight; tile0 -> LDS0
  ISSUE(a0A, a1A, bA, 0);
  ISSUE(a0B, a1B, bB, 1);
  STORE(a0A, a1A, bA, 0);   // compiler emits counted vmcnt(3): set1 stays in flight
  BAR();

  // main: pairs kt=0..29; issue kt+2 before compute; write tile kt+1; never vmcnt(0)
  for (int t2 = 0; t2 < 15; ++t2) {
    ISSUE(a0A, a1A, bA, t2 * 2 + 2);
    COMPUTE(0);
    STORE(a0B, a1B, bB, 8192);
    BAR();
    ISSUE(a0B, a1B, bB, t2 * 2 + 3);
    COMPUTE(8192);
    STORE(a0A, a1A, bA, 0);
    BAR();
  }
  // kt=30: no issue; write tile31 (auto vmcnt drains set1 only)
  COMPUTE(0);
  STORE(a0B, a1B, bB, 8192);
  BAR();
  // kt=31
  COMPUTE(8192);

#undef ISSUE
#undef STORE
#undef COMPUTE
#undef BAR

  // Epilogue: per-row sum of tanh(acc + addv[b][col]) * w_out[col]
  // C/D layout: col = lane&15, row = (lane>>4)*4 + reg
  const int b = bm >> 3;
  const float* addvb = addv + b * 512;
  float rowsum[4][4];
#pragma unroll
  for (int m = 0; m < 4; ++m)
#pragma unroll
    for (int reg = 0; reg < 4; ++reg) rowsum[m][reg] = 0.f;

#pragma unroll
  for (int m = 0; m < 4; ++m) {
#pragma unroll
    for (int n = 0; n < 2; ++n) {
      int col = col0 + wcol * 32 + n * 16 + lr;
      float av = addvb[col];
      float wo = w_out[col];
#pragma unroll
      for (int reg = 0; reg < 4; ++reg)
        rowsum[m][reg] += fast_tanh(acc[m][n][reg] + av) * wo;
    }
  }
#pragma unroll
  for (int m = 0; m < 4; ++m)
#pragma unroll
    for (int reg = 0; reg < 4; ++reg) {
      float v = rowsum[m][reg];
      v += __shfl_xor(v, 1, 64);
      v += __shfl_xor(v, 2, 64);
      v += __shfl_xor(v, 4, 64);
      v += __shfl_xor(v, 8, 64);
      rowsum[m][reg] = v;
    }
  if (lr == 0) {
#pragma unroll
    for (int m = 0; m < 4; ++m)
#pragma unroll
      for (int reg = 0; reg < 4; ++reg)
        red[(wrow * 64 + m * 16 + lkb * 4 + reg) * 4 + wcol] = rowsum[m][reg];
  }
  __syncthreads();
  if (tid < 128)
    psc[(long)bn * 65536 + row0 + tid] =
        red[tid * 4] + red[tid * 4 + 1] + red[tid * 4 + 2] + red[tid * 4 + 3];
}

// ---------------- Kernel C: softmax over S=1024 per batch
__global__ __launch_bounds__(256) void softmax_kernel(const float* __restrict__ psc,
                                                      float* __restrict__ wts) {
  int b = blockIdx.x, tid = threadIdx.x;
  __shared__ float sred[8];
  float sc[4];
  float mx = -1e30f;
#pragma unroll
  for (int i = 0; i < 4; ++i) {
    long r = (long)b * 1024 + tid + i * 256;
    sc[i] = psc[r] + psc[65536 + r] + psc[2 * 65536 + r] + psc[3 * 65536 + r];
    mx = fmaxf(mx, sc[i]);
  }
  for (int off = 1; off < 64; off <<= 1) mx = fmaxf(mx, __shfl_xor(mx, off, 64));
  if ((tid & 63) == 0) sred[tid >> 6] = mx;
  __syncthreads();
  mx = fmaxf(fmaxf(sred[0], sred[1]), fmaxf(sred[2], sred[3]));
  float e[4], sum = 0.f;
#pragma unroll
  for (int i = 0; i < 4; ++i) {
    e[i] = __expf(sc[i] - mx);
    sum += e[i];
  }
  for (int off = 1; off < 64; off <<= 1) sum += __shfl_xor(sum, off, 64);
  if ((tid & 63) == 0) sred[4 + (tid >> 6)] = sum;
  __syncthreads();
  sum = sred[4] + sred[5] + sred[6] + sred[7];
  float inv = 1.f / sum;
#pragma unroll
  for (int i = 0; i < 4; ++i) wts[(long)b * 1024 + tid + i * 256] = e[i] * inv;
}

// ---------------- Kernel D: attention partials over 8 chunks of 128 s
__global__ __launch_bounds__(256) void att_part_kernel(const float* __restrict__ encoded,
                                                       const float* __restrict__ wts,
                                                       float* __restrict__ attp) {
  int chunk = blockIdx.x;  // 8
  int b = blockIdx.y;      // 64
  int tid = threadIdx.x;
  f32x4 acc0 = (f32x4){0.f, 0.f, 0.f, 0.f};
  f32x4 acc1 = (f32x4){0.f, 0.f, 0.f, 0.f};
  const float* base = encoded + ((long)b * 1024 + chunk * 128) * 1024 + tid * 4;
  const float* w = wts + b * 1024 + chunk * 128;
#pragma unroll 4
  for (int s = 0; s < 128; s += 2) {
    acc0 += *(const f32x4*)(base + (long)s * 1024) * w[s];
    acc1 += *(const f32x4*)(base + (long)(s + 1) * 1024) * w[s + 1];
  }
  *(f32x4*)(attp + ((long)(b * 8 + chunk)) * 1024 + tid * 4) = acc0 + acc1;
}

// ---------------- Kernel E: xcat[b][0:512]=inputs, xcat[b][512:1536]=sum_chunk attp
__global__ __launch_bounds__(256) void xcat_kernel(const float* __restrict__ inputs,
                                                   const float* __restrict__ attp,
                                                   float* __restrict__ xcat) {
  int b = blockIdx.y;
  int k = blockIdx.x * 256 + threadIdx.x;  // 0..1535
  float v;
  if (k < 512) {
    v = inputs[b * 512 + k];
  } else {
    int h = k - 512;
    v = 0.f;
#pragma unroll
    for (int c = 0; c < 8; ++c) v += attp[((long)(b * 8 + c)) * 1024 + h];
  }
  xcat[(long)b * 1536 + k] = v;
}

// ---------------- Kernel F: GRU GEMVs, batch-grouped: chunk-group pinned to one XCD
__global__ __launch_bounds__(512) void gru_gemv_kernel(
    const float* __restrict__ xcat, const float* __restrict__ states,
    const float* __restrict__ W_ih, const float* __restrict__ b_ih,
    const float* __restrict__ W_hh, const float* __restrict__ b_hh,
    float* __restrict__ gi, float* __restrict__ gh) {
  __shared__ float sx[12288];  // 8 batches x 1536 (max)
  const int dd = blockIdx.x;            // 192
  const int xcd = dd & 7;
  const int n = dd >> 3;                // 0..23
  const int cgrp = xcd + 8 * (n >> 3);  // 0..23, pinned to xcd
  const int bg = n & 7;
  const int tid = threadIdx.x;
  const int lcol = tid & 255;
  const int bsel = (tid >> 8) * 4;      // 0 or 4

  if (cgrp < 12) {
    const int col = cgrp * 256 + lcol;
    const float* xb = xcat + (long)bg * 8 * 1536;
    for (int i = tid; i < 3072; i += 512) ((f32x4*)sx)[i] = ((const f32x4*)xb)[i];
    __syncthreads();
    float a0 = b_ih[col], a1 = a0, a2 = a0, a3 = a0;
    const float* x0 = sx + (bsel + 0) * 1536;
    const float* x1 = sx + (bsel + 1) * 1536;
    const float* x2 = sx + (bsel + 2) * 1536;
    const float* x3 = sx + (bsel + 3) * 1536;
    for (int k = 0; k < 1536; k += 4) {
      f32x4 v0 = *(const f32x4*)(x0 + k);
      f32x4 v1 = *(const f32x4*)(x1 + k);
      f32x4 v2 = *(const f32x4*)(x2 + k);
      f32x4 v3 = *(const f32x4*)(x3 + k);
#pragma unroll
      for (int j = 0; j < 4; ++j) {
        float w = W_ih[(long)(k + j) * 3072 + col];
        a0 += v0[j] * w; a1 += v1[j] * w; a2 += v2[j] * w; a3 += v3[j] * w;
      }
    }
    long o = (long)(bg * 8 + bsel) * 3072 + col;
    gi[o] = a0; gi[o + 3072] = a1; gi[o + 6144] = a2; gi[o + 9216] = a3;
  } else {
    const int col = (cgrp - 12) * 256 + lcol;
    const float* sb = states + (long)bg * 8 * 1024;
    for (int i = tid; i < 2048; i += 512) ((f32x4*)sx)[i] = ((const f32x4*)sb)[i];
    __syncthreads();
    float a0 = b_hh[col], a1 = a0, a2 = a0, a3 = a0;
    const float* x0 = sx + (bsel + 0) * 1024;
    const float* x1 = sx + (bsel + 1) * 1024;
    const float* x2 = sx + (bsel + 2) * 1024;
    const float* x3 = sx + (bsel + 3) * 1024;
    for (int k = 0; k < 1024; k += 4) {
      f32x4 v0 = *(const f32x4*)(x0 + k);
      f32x4 v1 = *(const f32x4*)(x1 + k);
      f32x4 v2 = *(const f32x4*)(x2 + k);
      f32x4 v3 = *(const f32x4*)(x3 + k);
#pragma unroll
      for (int j = 0; j < 4; ++j) {
        float w = W_hh[(long)(k + j) * 3072 + col];
        a0 += v0[j] * w; a1 += v1[j] * w; a2 += v2[j] * w; a3 += v3[j] * w;
      }
    }
    long o = (long)(bg * 8 + bsel) * 3072 + col;
    gh[o] = a0; gh[o + 3072] = a1; gh[o + 6144] = a2; gh[o + 9216] = a3;
  }
}

// ---------------- Kernel G: gates
__global__ __launch_bounds__(256) void gate_kernel(const float* __restrict__ gi,
                                                   const float* __restrict__ gh,
                                                   const float* __restrict__ states,
                                                   float* __restrict__ out) {
  int b = blockIdx.y;
  int j = blockIdx.x * 256 + threadIdx.x;  // 0..1023
  long o = (long)b * 3072;
  float ir = gi[o + j], hr = gh[o + j];
  float iz = gi[o + 1024 + j], hz = gh[o + 1024 + j];
  float in_ = gi[o + 2048 + j], hn = gh[o + 2048 + j];
  float r = 1.f / (1.f + __expf(-(ir + hr)));
  float z = 1.f / (1.f + __expf(-(iz + hz)));
  float n = fast_tanh(in_ + r * hn);
  out[(long)b * 1024 + j] = (1.f - z) * n + z * states[(long)b * 1024 + j];
}

extern "C" void kernel_launch(void* const* d_in, const int* in_sizes, int n_in,
                              void* d_out, int out_size, void* d_ws, size_t ws_size,
                              hipStream_t stream) {
  const float* inputs  = (const float*)d_in[0];
  const float* states  = (const float*)d_in[1];
  const float* encoded = (const float*)d_in[2];
  const float* W_enc   = (const float*)d_in[3];
  const float* b_enc   = (const float*)d_in[4];
  const float* W_dec   = (const float*)d_in[5];
  const float* b_dec   = (const float*)d_in[6];
  const float* w_out   = (const float*)d_in[7];
  // d_in[8] = b_out: softmax-invariant, unused
  const float* W_ih    = (const float*)d_in[9];
  const float* b_ih    = (const float*)d_in[10];
  const float* W_hh    = (const float*)d_in[11];
  const float* b_hh    = (const float*)d_in[12];
  float* out = (float*)d_out;
  float* ws = (float*)d_ws;

  float* addv = ws;                 // 32768
  float* psc  = ws + 32768;         // 262144
  float* wts  = ws + 294912;        // 65536
  float* attp = ws + 360448;        // 64*8*1024 = 524288
  float* xcat = ws + 884736;        // 98304
  float* gi   = ws + 983040;        // 196608
  float* gh   = ws + 1179648;       // 196608
  __bf16* Wt  = (__bf16*)(ws + 1376256);  // 512*1024 bf16
  // total 1638400 floats = 6.55 MB

  wenc_t_kernel<<<dim3(32, 16), 256, 0, stream>>>(W_enc, Wt);

  dim3 gA(64, 2);
  dec_proj_kernel<<<gA, 256, 0, stream>>>(states, W_dec, b_enc, b_dec, addv);

  enc_score_kernel<<<2048, 512, 0, stream>>>(encoded, Wt, addv, w_out, psc);

  softmax_kernel<<<64, 256, 0, stream>>>(psc, wts);

  dim3 gD(8, 64);
  att_part_kernel<<<gD, 256, 0, stream>>>(encoded, wts, attp);

  dim3 gE(6, 64);
  xcat_kernel<<<gE, 256, 0, stream>>>(inputs, attp, xcat);

  gru_gemv_kernel<<<192, 512, 0, stream>>>(xcat, states, W_ih, b_ih, W_hh, b_hh, gi, gh);

  dim3 gG(4, 64);
  gate_kernel<<<gG, 256, 0, stream>>>(gi, gh, states, out);
}

// Round 4
// 327.171 us; speedup vs baseline: 1.0045x; 1.0045x over previous
//
#include <hip/hip_runtime.h>
#include <hip/hip_bf16.h>

// Problem: B=64, S=1024, H=1024, A=512, E=512
// scores = tanh(encoded@W_enc + b_enc + states@W_dec + b_dec) . w_out (+b_out: softmax-invariant)
// weights = softmax(scores); attention = weights . encoded
// GRU: x=[inputs,attention]; gi=x@W_ih+b_ih; gh=states@W_hh+b_hh; gates -> h_new

typedef __attribute__((ext_vector_type(8))) __bf16 bf16x8;
typedef __attribute__((ext_vector_type(4))) __bf16 bf16x4;
typedef __attribute__((ext_vector_type(4))) float f32x4;

__device__ __forceinline__ float fast_tanh(float x) {
  float xa = fminf(fmaxf(x, -15.f), 15.f);
  float e = __expf(2.f * xa);
  return (e - 1.f) / (e + 1.f);
}

// ---------------- Kernel T: transpose+convert W_enc [1024][512] f32 -> Wt [512][1024] bf16
__global__ __launch_bounds__(256) void wenc_t_kernel(const float* __restrict__ W,
                                                     __bf16* __restrict__ Wt) {
  __shared__ float tile[32][33];
  int k0 = blockIdx.x * 32, a0 = blockIdx.y * 32;
  int tid = threadIdx.x;
  int r = tid >> 3, c4 = (tid & 7) * 4;
  f32x4 v = *(const f32x4*)(W + (long)(k0 + r) * 512 + a0 + c4);
  tile[r][c4 + 0] = v.x; tile[r][c4 + 1] = v.y;
  tile[r][c4 + 2] = v.z; tile[r][c4 + 3] = v.w;
  __syncthreads();
  int a = tid >> 3, k4 = (tid & 7) * 4;
  bf16x4 o = { (__bf16)tile[k4 + 0][a], (__bf16)tile[k4 + 1][a],
               (__bf16)tile[k4 + 2][a], (__bf16)tile[k4 + 3][a] };
  *(bf16x4*)(Wt + (long)(a0 + a) * 1024 + k0 + k4) = o;
}

// ---------------- Kernel A: addv[b][a] = b_enc[a]+b_dec[a]+sum_h states[b,h]*W_dec[h,a]
__global__ __launch_bounds__(256) void dec_proj_kernel(
    const float* __restrict__ states, const float* __restrict__ W_dec,
    const float* __restrict__ b_enc, const float* __restrict__ b_dec,
    float* __restrict__ addv) {
  int b = blockIdx.x, tid = threadIdx.x;
  int a = blockIdx.y * 256 + tid;
  __shared__ float sl[1024];
  for (int i = tid; i < 1024; i += 256) sl[i] = states[b * 1024 + i];
  __syncthreads();
  float c0 = 0.f, c1 = 0.f, c2 = 0.f, c3 = 0.f;
#pragma unroll 4
  for (int i = 0; i < 256; ++i) {
    c0 += sl[i]         * W_dec[(i)        * 512 + a];
    c1 += sl[i + 256]   * W_dec[(i + 256)  * 512 + a];
    c2 += sl[i + 512]   * W_dec[(i + 512)  * 512 + a];
    c3 += sl[i + 768]   * W_dec[(i + 768)  * 512 + a];
  }
  addv[b * 512 + a] = c0 + c1 + c2 + c3 + b_enc[a] + b_dec[a];
}

// ---------------- Kernel B: 128x128 tile, BK=64, 8 waves (2x4), depth-2 PINNED reg prefetch,
// counted vmcnt at STORE (never drained in loop), 2 lgkm sub-phases x 8 MFMA per barrier,
// XOR-swizzled LDS (proven 0-conflict), setprio around MFMA.
// LDS 64KB: A0@0 A1@16384 B0@32768 B1@49152 (each 128 rows x 128B); red reuses @0 at epilogue.
struct Stage { f32x4 a[4]; bf16x8 b[2]; };

__global__ __launch_bounds__(512, 4) void enc_score_kernel(
    const float* __restrict__ encoded,  // [65536][1024] f32
    const __bf16* __restrict__ Wt,      // [512][1024] bf16 (W_enc^T)
    const float* __restrict__ addv,     // [64][512]
    const float* __restrict__ w_out,    // [512]
    float* __restrict__ psc)            // [4][65536]
{
  __shared__ __attribute__((aligned(16))) char smem[65536];
  float* red = (float*)smem;  // reused after K-loop

  const int d = blockIdx.x;
  const int xcd = d & 7;
  const int slot = d >> 3;
  const int bn = slot & 3;
  const int bm = ((slot >> 2) << 3) | xcd;  // bn-siblings share bm AND xcd

  const int tid = threadIdx.x;
  const int lane = tid & 63;
  const int wid = tid >> 6;       // 0..7
  const int wrow = wid >> 2;      // 0..1 (64 rows)
  const int wcol = wid & 3;       // 0..3 (32 cols)
  const int lr = lane & 15;
  const int lkb = lane >> 4;      // 0..3

  const long row0 = (long)bm * 128;
  const int col0 = bn * 128;

  // staging: 4 threads per row, each 16 k (A: 64B fp32 -> 2x bf16x8; B: 32B bf16 -> 2x bf16x8)
  const int arow = tid >> 2, akq = tid & 3;
  const int bcol = tid >> 2, bkq = tid & 3;
  const float* aBase = encoded + (row0 + arow) * 1024 + akq * 16;
  const __bf16* bBase = Wt + (long)(col0 + bcol) * 1024 + bkq * 16;
  const int asw = (arow & 7) << 4;
  const int aw0 = arow * 128 + ((akq * 32) ^ asw);
  const int aw1 = arow * 128 + ((akq * 32 + 16) ^ asw);
  const int bsw = (bcol & 7) << 4;
  const int bw0 = bcol * 128 + ((bkq * 32) ^ bsw);
  const int bw1 = bcol * 128 + ((bkq * 32 + 16) ^ bsw);

  // fragment read offsets: byte = rowbase + m*2048 + (rdSw ^ (ks<<6))
  const int rdSw = (lkb << 4) ^ ((lr & 7) << 4);
  const int aRow = (wrow * 64 + lr) * 128;
  const int bRow = (wcol * 32 + lr) * 128;

  f32x4 acc[4][2];
#pragma unroll
  for (int m = 0; m < 4; ++m)
#pragma unroll
    for (int n = 0; n < 2; ++n) acc[m][n] = (f32x4){0.f, 0.f, 0.f, 0.f};

  Stage X, Y;

#define ISSUE(S, KT) do { \
    _Pragma("unroll") for (int _j = 0; _j < 4; ++_j) \
      S.a[_j] = *(const f32x4*)(aBase + (KT) * 64 + _j * 4); \
    _Pragma("unroll") for (int _j = 0; _j < 2; ++_j) \
      S.b[_j] = *(const bf16x8*)(bBase + (KT) * 64 + _j * 8); \
    __builtin_amdgcn_sched_barrier(0); \
  } while (0)

#define STORE(S, ABUF) do { \
    bf16x8 _w0, _w1; \
    _Pragma("unroll") for (int _i = 0; _i < 4; ++_i) { \
      _w0[_i] = (__bf16)S.a[0][_i]; _w0[_i + 4] = (__bf16)S.a[1][_i]; \
      _w1[_i] = (__bf16)S.a[2][_i]; _w1[_i + 4] = (__bf16)S.a[3][_i]; } \
    *(bf16x8*)(smem + (ABUF) + aw0) = _w0; \
    *(bf16x8*)(smem + (ABUF) + aw1) = _w1; \
    *(bf16x8*)(smem + 32768 + (ABUF) + bw0) = S.b[0]; \
    *(bf16x8*)(smem + 32768 + (ABUF) + bw1) = S.b[1]; \
    __builtin_amdgcn_sched_barrier(0); \
  } while (0)

#define COMPUTE(ABUF) do { \
    _Pragma("unroll") for (int _ks = 0; _ks < 2; ++_ks) { \
      bf16x8 _af[4], _bf[2]; \
      _Pragma("unroll") for (int _m = 0; _m < 4; ++_m) \
        _af[_m] = *(const bf16x8*)(smem + (ABUF) + aRow + _m * 2048 + (rdSw ^ (_ks << 6))); \
      _Pragma("unroll") for (int _n = 0; _n < 2; ++_n) \
        _bf[_n] = *(const bf16x8*)(smem + 32768 + (ABUF) + bRow + _n * 2048 + (rdSw ^ (_ks << 6))); \
      asm volatile("s_waitcnt lgkmcnt(0)" ::: "memory"); \
      __builtin_amdgcn_sched_barrier(0); \
      __builtin_amdgcn_s_setprio(1); \
      _Pragma("unroll") for (int _m = 0; _m < 4; ++_m) \
        _Pragma("unroll") for (int _n = 0; _n < 2; ++_n) \
          acc[_m][_n] = __builtin_amdgcn_mfma_f32_16x16x32_bf16(_af[_m], _bf[_n], acc[_m][_n], 0, 0, 0); \
      __builtin_amdgcn_s_setprio(0); \
      __builtin_amdgcn_sched_barrier(0); \
    } \
  } while (0)

#define BAR() do { \
    asm volatile("s_waitcnt lgkmcnt(0)" ::: "memory"); \
    __builtin_amdgcn_sched_barrier(0); \
    __builtin_amdgcn_s_barrier(); \
    __builtin_amdgcn_sched_barrier(0); \
  } while (0)

  // prologue: tiles 0,1 in flight; tile0 -> buf0 (counted vmcnt(6): tile1 stays in flight)
  ISSUE(X, 0);
  ISSUE(Y, 1);
  STORE(X, 0);
  BAR();

  for (int t2 = 0; t2 < 7; ++t2) {
    ISSUE(X, 2 * t2 + 2);
    COMPUTE(0);          // kt = 2*t2
    STORE(Y, 16384);
    BAR();
    ISSUE(Y, 2 * t2 + 3);
    COMPUTE(16384);      // kt = 2*t2+1
    STORE(X, 0);
    BAR();
  }
  COMPUTE(0);            // kt = 14
  STORE(Y, 16384);
  BAR();
  COMPUTE(16384);        // kt = 15

#undef ISSUE
#undef STORE
#undef COMPUTE
#undef BAR

  // Epilogue: per-row sum of tanh(acc + addv[b][col]) * w_out[col]
  // C/D layout: col = lane&15, row = (lane>>4)*4 + reg
  const int b = bm >> 3;
  const float* addvb = addv + b * 512;
  float rowsum[4][4];
#pragma unroll
  for (int m = 0; m < 4; ++m)
#pragma unroll
    for (int reg = 0; reg < 4; ++reg) rowsum[m][reg] = 0.f;

#pragma unroll
  for (int m = 0; m < 4; ++m) {
#pragma unroll
    for (int n = 0; n < 2; ++n) {
      int col = col0 + wcol * 32 + n * 16 + lr;
      float av = addvb[col];
      float wo = w_out[col];
#pragma unroll
      for (int reg = 0; reg < 4; ++reg)
        rowsum[m][reg] += fast_tanh(acc[m][n][reg] + av) * wo;
    }
  }
#pragma unroll
  for (int m = 0; m < 4; ++m)
#pragma unroll
    for (int reg = 0; reg < 4; ++reg) {
      float v = rowsum[m][reg];
      v += __shfl_xor(v, 1, 64);
      v += __shfl_xor(v, 2, 64);
      v += __shfl_xor(v, 4, 64);
      v += __shfl_xor(v, 8, 64);
      rowsum[m][reg] = v;
    }
  if (lr == 0) {
#pragma unroll
    for (int m = 0; m < 4; ++m)
#pragma unroll
      for (int reg = 0; reg < 4; ++reg)
        red[(wrow * 64 + m * 16 + lkb * 4 + reg) * 4 + wcol] = rowsum[m][reg];
  }
  __syncthreads();
  if (tid < 128)
    psc[(long)bn * 65536 + row0 + tid] =
        red[tid * 4] + red[tid * 4 + 1] + red[tid * 4 + 2] + red[tid * 4 + 3];
}

// ---------------- Kernel C: softmax over S=1024 per batch
__global__ __launch_bounds__(256) void softmax_kernel(const float* __restrict__ psc,
                                                      float* __restrict__ wts) {
  int b = blockIdx.x, tid = threadIdx.x;
  __shared__ float sred[8];
  float sc[4];
  float mx = -1e30f;
#pragma unroll
  for (int i = 0; i < 4; ++i) {
    long r = (long)b * 1024 + tid + i * 256;
    sc[i] = psc[r] + psc[65536 + r] + psc[2 * 65536 + r] + psc[3 * 65536 + r];
    mx = fmaxf(mx, sc[i]);
  }
  for (int off = 1; off < 64; off <<= 1) mx = fmaxf(mx, __shfl_xor(mx, off, 64));
  if ((tid & 63) == 0) sred[tid >> 6] = mx;
  __syncthreads();
  mx = fmaxf(fmaxf(sred[0], sred[1]), fmaxf(sred[2], sred[3]));
  float e[4], sum = 0.f;
#pragma unroll
  for (int i = 0; i < 4; ++i) {
    e[i] = __expf(sc[i] - mx);
    sum += e[i];
  }
  for (int off = 1; off < 64; off <<= 1) sum += __shfl_xor(sum, off, 64);
  if ((tid & 63) == 0) sred[4 + (tid >> 6)] = sum;
  __syncthreads();
  sum = sred[4] + sred[5] + sred[6] + sred[7];
  float inv = 1.f / sum;
#pragma unroll
  for (int i = 0; i < 4; ++i) wts[(long)b * 1024 + tid + i * 256] = e[i] * inv;
}

// ---------------- Kernel D: attention partials over 16 chunks of 64 s (1024 blocks, 4-deep ILP)
__global__ __launch_bounds__(256) void att_part_kernel(const float* __restrict__ encoded,
                                                       const float* __restrict__ wts,
                                                       float* __restrict__ attp) {
  int chunk = blockIdx.x;  // 16
  int b = blockIdx.y;      // 64
  int tid = threadIdx.x;
  f32x4 a0 = (f32x4){0.f, 0.f, 0.f, 0.f};
  f32x4 a1 = a0, a2 = a0, a3 = a0;
  const float* base = encoded + ((long)b * 1024 + chunk * 64) * 1024 + tid * 4;
  const float* w = wts + b * 1024 + chunk * 64;
#pragma unroll 4
  for (int s = 0; s < 64; s += 4) {
    f32x4 v0 = *(const f32x4*)(base + (long)(s + 0) * 1024);
    f32x4 v1 = *(const f32x4*)(base + (long)(s + 1) * 1024);
    f32x4 v2 = *(const f32x4*)(base + (long)(s + 2) * 1024);
    f32x4 v3 = *(const f32x4*)(base + (long)(s + 3) * 1024);
    a0 += v0 * w[s]; a1 += v1 * w[s + 1]; a2 += v2 * w[s + 2]; a3 += v3 * w[s + 3];
  }
  *(f32x4*)(attp + ((long)(b * 16 + chunk)) * 1024 + tid * 4) = (a0 + a1) + (a2 + a3);
}

// ---------------- Kernel E: xcat[b][0:512]=inputs, xcat[b][512:1536]=sum_chunk attp
__global__ __launch_bounds__(256) void xcat_kernel(const float* __restrict__ inputs,
                                                   const float* __restrict__ attp,
                                                   float* __restrict__ xcat) {
  int b = blockIdx.y;
  int k = blockIdx.x * 256 + threadIdx.x;  // 0..1535
  float v;
  if (k < 512) {
    v = inputs[b * 512 + k];
  } else {
    int h = k - 512;
    v = 0.f;
#pragma unroll
    for (int c = 0; c < 16; ++c) v += attp[((long)(b * 16 + c)) * 1024 + h];
  }
  xcat[(long)b * 1536 + k] = v;
}

// ---------------- Kernel F: GRU GEMVs, batch-grouped: chunk-group pinned to one XCD
__global__ __launch_bounds__(512) void gru_gemv_kernel(
    const float* __restrict__ xcat, const float* __restrict__ states,
    const float* __restrict__ W_ih, const float* __restrict__ b_ih,
    const float* __restrict__ W_hh, const float* __restrict__ b_hh,
    float* __restrict__ gi, float* __restrict__ gh) {
  __shared__ float sx[12288];  // 8 batches x 1536 (max)
  const int dd = blockIdx.x;            // 192
  const int xcd = dd & 7;
  const int n = dd >> 3;                // 0..23
  const int cgrp = xcd + 8 * (n >> 3);  // 0..23, pinned to xcd
  const int bg = n & 7;
  const int tid = threadIdx.x;
  const int lcol = tid & 255;
  const int bsel = (tid >> 8) * 4;      // 0 or 4

  if (cgrp < 12) {
    const int col = cgrp * 256 + lcol;
    const float* xb = xcat + (long)bg * 8 * 1536;
    for (int i = tid; i < 3072; i += 512) ((f32x4*)sx)[i] = ((const f32x4*)xb)[i];
    __syncthreads();
    float a0 = b_ih[col], a1 = a0, a2 = a0, a3 = a0;
    const float* x0 = sx + (bsel + 0) * 1536;
    const float* x1 = sx + (bsel + 1) * 1536;
    const float* x2 = sx + (bsel + 2) * 1536;
    const float* x3 = sx + (bsel + 3) * 1536;
    for (int k = 0; k < 1536; k += 4) {
      f32x4 v0 = *(const f32x4*)(x0 + k);
      f32x4 v1 = *(const f32x4*)(x1 + k);
      f32x4 v2 = *(const f32x4*)(x2 + k);
      f32x4 v3 = *(const f32x4*)(x3 + k);
#pragma unroll
      for (int j = 0; j < 4; ++j) {
        float w = W_ih[(long)(k + j) * 3072 + col];
        a0 += v0[j] * w; a1 += v1[j] * w; a2 += v2[j] * w; a3 += v3[j] * w;
      }
    }
    long o = (long)(bg * 8 + bsel) * 3072 + col;
    gi[o] = a0; gi[o + 3072] = a1; gi[o + 6144] = a2; gi[o + 9216] = a3;
  } else {
    const int col = (cgrp - 12) * 256 + lcol;
    const float* sb = states + (long)bg * 8 * 1024;
    for (int i = tid; i < 2048; i += 512) ((f32x4*)sx)[i] = ((const f32x4*)sb)[i];
    __syncthreads();
    float a0 = b_hh[col], a1 = a0, a2 = a0, a3 = a0;
    const float* x0 = sx + (bsel + 0) * 1024;
    const float* x1 = sx + (bsel + 1) * 1024;
    const float* x2 = sx + (bsel + 2) * 1024;
    const float* x3 = sx + (bsel + 3) * 1024;
    for (int k = 0; k < 1024; k += 4) {
      f32x4 v0 = *(const f32x4*)(x0 + k);
      f32x4 v1 = *(const f32x4*)(x1 + k);
      f32x4 v2 = *(const f32x4*)(x2 + k);
      f32x4 v3 = *(const f32x4*)(x3 + k);
#pragma unroll
      for (int j = 0; j < 4; ++j) {
        float w = W_hh[(long)(k + j) * 3072 + col];
        a0 += v0[j] * w; a1 += v1[j] * w; a2 += v2[j] * w; a3 += v3[j] * w;
      }
    }
    long o = (long)(bg * 8 + bsel) * 3072 + col;
    gh[o] = a0; gh[o + 3072] = a1; gh[o + 6144] = a2; gh[o + 9216] = a3;
  }
}

// ---------------- Kernel G: gates
__global__ __launch_bounds__(256) void gate_kernel(const float* __restrict__ gi,
                                                   const float* __restrict__ gh,
                                                   const float* __restrict__ states,
                                                   float* __restrict__ out) {
  int b = blockIdx.y;
  int j = blockIdx.x * 256 + threadIdx.x;  // 0..1023
  long o = (long)b * 3072;
  float ir = gi[o + j], hr = gh[o + j];
  float iz = gi[o + 1024 + j], hz = gh[o + 1024 + j];
  float in_ = gi[o + 2048 + j], hn = gh[o + 2048 + j];
  float r = 1.f / (1.f + __expf(-(ir + hr)));
  float z = 1.f / (1.f + __expf(-(iz + hz)));
  float n = fast_tanh(in_ + r * hn);
  out[(long)b * 1024 + j] = (1.f - z) * n + z * states[(long)b * 1024 + j];
}

extern "C" void kernel_launch(void* const* d_in, const int* in_sizes, int n_in,
                              void* d_out, int out_size, void* d_ws, size_t ws_size,
                              hipStream_t stream) {
  const float* inputs  = (const float*)d_in[0];
  const float* states  = (const float*)d_in[1];
  const float* encoded = (const float*)d_in[2];
  const float* W_enc   = (const float*)d_in[3];
  const float* b_enc   = (const float*)d_in[4];
  const float* W_dec   = (const float*)d_in[5];
  const float* b_dec   = (const float*)d_in[6];
  const float* w_out   = (const float*)d_in[7];
  // d_in[8] = b_out: softmax-invariant, unused
  const float* W_ih    = (const float*)d_in[9];
  const float* b_ih    = (const float*)d_in[10];
  const float* W_hh    = (const float*)d_in[11];
  const float* b_hh    = (const float*)d_in[12];
  float* out = (float*)d_out;
  float* ws = (float*)d_ws;

  float* addv = ws;                 // 32768
  float* psc  = ws + 32768;         // 262144
  float* wts  = ws + 294912;        // 65536
  float* attp = ws + 360448;        // 64*16*1024 = 1048576
  float* xcat = ws + 1409024;       // 98304
  float* gi   = ws + 1507328;       // 196608
  float* gh   = ws + 1703936;       // 196608
  __bf16* Wt  = (__bf16*)(ws + 1900544);  // 512*1024 bf16 (262144 float slots)
  // total 2162688 floats = 8.65 MB

  wenc_t_kernel<<<dim3(32, 16), 256, 0, stream>>>(W_enc, Wt);

  dim3 gA(64, 2);
  dec_proj_kernel<<<gA, 256, 0, stream>>>(states, W_dec, b_enc, b_dec, addv);

  enc_score_kernel<<<2048, 512, 0, stream>>>(encoded, Wt, addv, w_out, psc);

  softmax_kernel<<<64, 256, 0, stream>>>(psc, wts);

  dim3 gD(16, 64);
  att_part_kernel<<<gD, 256, 0, stream>>>(encoded, wts, attp);

  dim3 gE(6, 64);
  xcat_kernel<<<gE, 256, 0, stream>>>(inputs, attp, xcat);

  gru_gemv_kernel<<<192, 512, 0, stream>>>(xcat, states, W_ih, b_ih, W_hh, b_hh, gi, gh);

  dim3 gG(4, 64);
  gate_kernel<<<gG, 256, 0, stream>>>(gi, gh, states, out);
}